// Round 12
// baseline (145.850 us; speedup 1.0000x reference)
//
#include <hip/hip_runtime.h>
#include <hip/hip_fp16.h>
#include <math.h>

#define NN 50000
#define NE 800000
#define NEG 0.2f

#define NPB 128            // partition blocks
#define CHK 6250           // NE / NPB
#define NBUK 98            // bucket = dst >> 9  (512 dst per bucket)
#define LCAP 10240         // per-bucket LDS capacity
#define GB 782             // lin blocks: ceil(NN/64)

typedef __attribute__((ext_vector_type(8))) short short8v;  // 8 bf16 (4 VGPRs)
typedef __attribute__((ext_vector_type(4))) float f32x4;    // MFMA C/D frag

__device__ __forceinline__ float lrelu(float x){ return x > 0.f ? x : NEG * x; }

__device__ __forceinline__ short bf16t(float x){ return (short)(__float_as_uint(x) >> 16); }
__device__ __forceinline__ float bf16tof(short s){
    return __uint_as_float(((unsigned)(unsigned short)s) << 16);
}

// ---------- MFMA linear body: H(fp16) = X@W^T + b, plus attention scalars ----------
__device__ __forceinline__ void lin_body(int blk, int tid,
                                         const float* __restrict__ X,
                                         const float* __restrict__ W,
                                         const float* __restrict__ b,
                                         const float* __restrict__ att,
                                         __half* __restrict__ Hh,
                                         float* __restrict__ ad,
                                         float* __restrict__ as_, int n){
    int lane = tid & 63, wid = tid >> 6;
    int nb = blk * 64 + wid * 16;
    if (nb >= n) return;
    int r0 = lane & 15, rg = lane >> 4;

    short8v a_hi[2], a_lo[2];
    int arow = nb + r0; if (arow >= n) arow = n - 1;
    const float* xp = X + (size_t)arow * 64 + rg * 8;
    #pragma unroll
    for (int ks = 0; ks < 2; ++ks){
        #pragma unroll
        for (int j = 0; j < 8; ++j){
            float v = xp[ks * 32 + j];
            short h = bf16t(v);
            a_hi[ks][j] = h;
            a_lo[ks][j] = bf16t(v - bf16tof(h));
        }
    }

    f32x4 acc[4] = {{0,0,0,0},{0,0,0,0},{0,0,0,0},{0,0,0,0}};
    #pragma unroll
    for (int nt = 0; nt < 4; ++nt){
        const float* wp = W + (size_t)(nt * 16 + r0) * 64 + rg * 8;
        #pragma unroll
        for (int ks = 0; ks < 2; ++ks){
            short8v b_hi, b_lo;
            #pragma unroll
            for (int j = 0; j < 8; ++j){
                float v = wp[ks * 32 + j];
                short h = bf16t(v);
                b_hi[j] = h;
                b_lo[j] = bf16t(v - bf16tof(h));
            }
            acc[nt] = __builtin_amdgcn_mfma_f32_16x16x32_bf16(a_hi[ks], b_hi, acc[nt], 0, 0, 0);
            acc[nt] = __builtin_amdgcn_mfma_f32_16x16x32_bf16(a_hi[ks], b_lo, acc[nt], 0, 0, 0);
            acc[nt] = __builtin_amdgcn_mfma_f32_16x16x32_bf16(a_lo[ks], b_hi, acc[nt], 0, 0, 0);
        }
    }

    #pragma unroll
    for (int nt = 0; nt < 4; ++nt){
        float bb = b[nt * 16 + r0];
        #pragma unroll
        for (int q = 0; q < 4; ++q){
            int node = nb + rg * 4 + q;
            float v = acc[nt][q] + bb;
            acc[nt][q] = v;
            if (node < n) Hh[(size_t)node * 64 + nt * 16 + r0] = __float2half(v);
        }
    }

    float attd[4], atts[4];
    #pragma unroll
    for (int nt = 0; nt < 4; ++nt){
        attd[nt] = att[nt * 16 + r0];
        atts[nt] = att[64 + nt * 16 + r0];
    }
    #pragma unroll
    for (int q = 0; q < 4; ++q){
        float pd = 0.f, ps = 0.f;
        #pragma unroll
        for (int nt = 0; nt < 4; ++nt){
            pd = fmaf(attd[nt], acc[nt][q], pd);
            ps = fmaf(atts[nt], acc[nt][q], ps);
        }
        #pragma unroll
        for (int off = 8; off; off >>= 1){
            pd += __shfl_xor(pd, off);
            ps += __shfl_xor(ps, off);
        }
        int node = nb + rg * 4 + q;
        if (r0 == 0 && node < n){ ad[node] = pd; as_[node] = ps; }
    }
}

// ---------- fused front: lin1 [0,GB) | cntA [GB,GB+NPB) | wcomb [GB+NPB] ----------
__global__ __launch_bounds__(256) void k_fuse0(const float* __restrict__ X,
                                               const float* __restrict__ W1,
                                               const float* __restrict__ b1,
                                               const float* __restrict__ att1,
                                               __half* __restrict__ Hh,
                                               float* __restrict__ ad,
                                               float* __restrict__ as_,
                                               const int* __restrict__ dst,
                                               int* __restrict__ counts,
                                               const float* __restrict__ Wp1,
                                               const float* __restrict__ bp1,
                                               const float* __restrict__ Wp2,
                                               const float* __restrict__ bp2,
                                               float* __restrict__ Wc,
                                               float* __restrict__ bc){
    __shared__ int c[NBUK];
    int tid = threadIdx.x, blk = blockIdx.x;
    if (blk < GB){
        lin_body(blk, tid, X, W1, b1, att1, Hh, ad, as_, NN);
    } else if (blk < GB + NPB){
        int cb = blk - GB;
        for (int i = tid; i < NBUK; i += 256) c[i] = 0;
        __syncthreads();
        int beg = cb * CHK, end = min(beg + CHK, NE);
        for (int i = beg + tid; i < end; i += 256) atomicAdd(&c[dst[i] >> 9], 1);
        __syncthreads();
        for (int i = tid; i < NBUK; i += 256) counts[i * NPB + cb] = c[i];
    } else {
        for (int idx = tid; idx < 2560; idx += 256){
            int cc = idx >> 6, k = idx & 63;
            float s = 0.f;
            #pragma unroll 8
            for (int j = 0; j < 64; ++j) s = fmaf(Wp2[cc * 64 + j], Wp1[j * 64 + k], s);
            Wc[idx] = s;
        }
        if (tid < 40){
            float s = bp2[tid];
            for (int j = 0; j < 64; ++j) s = fmaf(Wp2[tid * 64 + j], bp1[j], s);
            bc[tid] = s;
        }
    }
}

// small in-block scan of totsh[98] -> bb (exclusive); threads 0..127 participate
__device__ __forceinline__ void bbase_scan(const int* tot, int* bb, int* wsum, int tid){
    int lane = tid & 63, w2 = tid >> 6;
    int vv = 0, incl = 0;
    if (tid < 128){
        vv = (tid < NBUK) ? tot[tid] : 0;
        incl = vv;
        #pragma unroll
        for (int off = 1; off < 64; off <<= 1){
            int t = __shfl_up(incl, off);
            if (lane >= off) incl += t;
        }
        if (lane == 63) wsum[w2] = incl;
    }
    __syncthreads();
    if (tid < NBUK) bb[tid] = incl - vv + (w2 ? wsum[0] : 0);
    __syncthreads();
}

// ---------- C: partition; per-block offsets computed in-block from raw counts ----------
__global__ __launch_bounds__(256) void k_partC(const int* __restrict__ src,
                                               const int* __restrict__ dst,
                                               const int* __restrict__ counts,
                                               unsigned* __restrict__ part){
    __shared__ int lcur[NBUK];
    __shared__ int totsh[NBUK];
    __shared__ int bb[NBUK];
    __shared__ int wsum[2];
    int tid = threadIdx.x, blk = blockIdx.x;
    if (tid < NBUK){
        const int* row = counts + tid * NPB;
        int pre = 0, tt = 0;
        for (int i = 0; i < NPB; ++i){
            int cc = row[i];
            tt += cc;
            pre += (i < blk) ? cc : 0;
        }
        totsh[tid] = tt;
        lcur[tid] = pre;
    }
    __syncthreads();
    bbase_scan(totsh, bb, wsum, tid);
    if (tid < NBUK) lcur[tid] += bb[tid];
    __syncthreads();
    int beg = blk * CHK, end = min(beg + CHK, NE);
    for (int i = beg + tid; i < end; i += 256){
        int d = dst[i];
        int pos = atomicAdd(&lcur[d >> 9], 1);
        part[pos] = ((unsigned)(d & 511) << 16) | (unsigned)src[i];
    }
}

// ---------- D: per-bucket CSR build; bases recomputed in-block ----------
__global__ __launch_bounds__(256) void k_buildD(const unsigned* __restrict__ part,
                                                const int* __restrict__ counts,
                                                int* __restrict__ rowstart,
                                                int* __restrict__ csr){
    __shared__ int hist[512], cur[512];
    __shared__ int csrbuf[LCAP];
    __shared__ int swave[4];
    __shared__ int totsh[NBUK];
    __shared__ int bb[NBUK];
    __shared__ int wsum2[2];
    int tid = threadIdx.x, lane = tid & 63, wid = tid >> 6;
    int b = blockIdx.x;
    if (tid < NBUK){
        const int* row = counts + tid * NPB;
        int tt = 0;
        for (int i = 0; i < NPB; ++i) tt += row[i];
        totsh[tid] = tt;
    }
    __syncthreads();
    bbase_scan(totsh, bb, wsum2, tid);
    int ebeg = bb[b], cnt = totsh[b];

    for (int i = tid; i < 512; i += 256) hist[i] = 0;
    __syncthreads();
    for (int i = tid; i < cnt; i += 256) atomicAdd(&hist[part[ebeg + i] >> 16], 1);
    __syncthreads();

    int h0 = hist[2 * tid], h1 = hist[2 * tid + 1];
    int v = h0 + h1, incl = v;
    #pragma unroll
    for (int off = 1; off < 64; off <<= 1){
        int t = __shfl_up(incl, off);
        if (lane >= off) incl += t;
    }
    if (lane == 63) swave[wid] = incl;
    __syncthreads();
    int woff = 0;
    #pragma unroll
    for (int w = 0; w < 4; ++w) if (w < wid) woff += swave[w];
    int e0 = woff + incl - v;
    int e1 = e0 + h0;
    cur[2 * tid] = e0; cur[2 * tid + 1] = e1;
    int gi = b * 512 + 2 * tid;
    if (gi     <= NN) rowstart[gi]     = ebeg + e0;
    if (gi + 1 <= NN) rowstart[gi + 1] = ebeg + e1;
    __syncthreads();

    for (int i = tid; i < cnt; i += 256){
        unsigned u = part[ebeg + i];
        int lp = atomicAdd(&cur[u >> 16], 1);
        if (lp < LCAP) csrbuf[lp] = (int)(u & 0xFFFFu);
    }
    __syncthreads();
    int m = min(cnt, LCAP);
    for (int i = tid; i < m; i += 256) csr[ebeg + i] = csrbuf[i];
}

// ---------- plain lin kernel (layer 2) ----------
__global__ __launch_bounds__(256) void k_lin_mfma(const float* __restrict__ X,
                                                  const float* __restrict__ W,
                                                  const float* __restrict__ b,
                                                  const float* __restrict__ att,
                                                  __half* __restrict__ Hh,
                                                  float* __restrict__ ad,
                                                  float* __restrict__ as_, int n){
    lin_body(blockIdx.x, threadIdx.x, X, W, b, att, Hh, ad, as_, n);
}

// ---------- GAT aggregation: one wave per node, LDS-staged s/e, float4 row loads ----------
// phase 1: dense 64-wide logits -> LDS. phase 2: lane = slot*8+seg; each 8-lane
// group consumes one edge's 128B row via float4 (8 halves) -> 8 edges per wave-load.
__global__ __launch_bounds__(256) void k_agg(const __half* __restrict__ H,
                                             const float* __restrict__ ad,
                                             const float* __restrict__ as_,
                                             const int* __restrict__ rowstart,
                                             const int* __restrict__ csr,
                                             const float* __restrict__ bias,
                                             float* __restrict__ OUT, int n){
    __shared__ float e_sh[4][64];
    __shared__ int   s_sh[4][64];
    int tid = threadIdx.x, lane = tid & 63, wid = tid >> 6;
    int node = blockIdx.x * 4 + wid;
    if (node >= n) return;
    int beg = rowstart[node], end = rowstart[node + 1];
    float adn = ad[node];
    int slot = lane >> 3, seg = lane & 7;

    float acc[8] = {0.f,0.f,0.f,0.f,0.f,0.f,0.f,0.f};
    float denom = 0.f;
    for (int cbeg = beg; cbeg < end; cbeg += 64){
        int k = cbeg + lane;
        bool valid = (k < end);
        int s = valid ? csr[k] : 0;
        float e = valid ? __expf(lrelu(adn + as_[s])) : 0.f;
        e_sh[wid][lane] = e;
        s_sh[wid][lane] = valid ? s : 0;
        float es = e;
        #pragma unroll
        for (int off = 32; off; off >>= 1) es += __shfl_xor(es, off);
        denom += es;
        int cnt = min(64, end - cbeg);
        // 8 edges per j-iteration; 8-lane group per edge; e=0 beyond cnt -> no-op
        #pragma unroll 2
        for (int j = 0; j < cnt; j += 8){
            int idx = j + slot;                       // <= 63 always
            int ss = s_sh[wid][idx];
            float ee = e_sh[wid][idx];
            float4 hv = *(const float4*)(H + (size_t)ss * 64 + seg * 8);
            const __half2* h2 = (const __half2*)&hv;
            float2 f0 = __half22float2(h2[0]), f1 = __half22float2(h2[1]);
            float2 f2 = __half22float2(h2[2]), f3 = __half22float2(h2[3]);
            acc[0] = fmaf(ee, f0.x, acc[0]); acc[1] = fmaf(ee, f0.y, acc[1]);
            acc[2] = fmaf(ee, f1.x, acc[2]); acc[3] = fmaf(ee, f1.y, acc[3]);
            acc[4] = fmaf(ee, f2.x, acc[4]); acc[5] = fmaf(ee, f2.y, acc[5]);
            acc[6] = fmaf(ee, f3.x, acc[6]); acc[7] = fmaf(ee, f3.y, acc[7]);
        }
    }
    // reduce across slot bits (8,16,32); seg groups independent
    #pragma unroll
    for (int off = 8; off < 64; off <<= 1){
        #pragma unroll
        for (int t = 0; t < 8; ++t) acc[t] += __shfl_xor(acc[t], off);
    }
    if (slot == 0){
        float inv = 1.f / (denom + 1e-16f);
        const float4* b4 = (const float4*)bias;       // seg = lane (0..7)
        float4 ba = b4[seg * 2], bb = b4[seg * 2 + 1];
        float4 o1, o2;
        o1.x = fmaxf(fmaf(acc[0], inv, ba.x), 0.f);
        o1.y = fmaxf(fmaf(acc[1], inv, ba.y), 0.f);
        o1.z = fmaxf(fmaf(acc[2], inv, ba.z), 0.f);
        o1.w = fmaxf(fmaf(acc[3], inv, ba.w), 0.f);
        o2.x = fmaxf(fmaf(acc[4], inv, bb.x), 0.f);
        o2.y = fmaxf(fmaf(acc[5], inv, bb.y), 0.f);
        o2.z = fmaxf(fmaf(acc[6], inv, bb.z), 0.f);
        o2.w = fmaxf(fmaf(acc[7], inv, bb.w), 0.f);
        float4* op = (float4*)(OUT + (size_t)node * 64);
        op[seg * 2]     = o1;
        op[seg * 2 + 1] = o2;
    }
}

// ---------- MFMA MLP: out = log_softmax(G@Wc^T + bc) ----------
__global__ __launch_bounds__(256) void k_mlp_mfma(const float* __restrict__ G,
                                                  const float* __restrict__ Wc,
                                                  const float* __restrict__ bc,
                                                  float* __restrict__ out, int n){
    int lane = threadIdx.x & 63, wid = threadIdx.x >> 6;
    int nb = blockIdx.x * 64 + wid * 16;
    if (nb >= n) return;
    int r0 = lane & 15, rg = lane >> 4;

    short8v a_hi[2], a_lo[2];
    int arow = nb + r0; if (arow >= n) arow = n - 1;
    const float* gp = G + (size_t)arow * 64 + rg * 8;
    #pragma unroll
    for (int ks = 0; ks < 2; ++ks){
        #pragma unroll
        for (int j = 0; j < 8; ++j){
            float v = gp[ks * 32 + j];
            short h = bf16t(v);
            a_hi[ks][j] = h;
            a_lo[ks][j] = bf16t(v - bf16tof(h));
        }
    }

    f32x4 acc[3] = {{0,0,0,0},{0,0,0,0},{0,0,0,0}};
    #pragma unroll
    for (int nt = 0; nt < 3; ++nt){
        int f = nt * 16 + r0;
        int fr = (f < 40) ? f : 39;
        const float* wp = Wc + (size_t)fr * 64 + rg * 8;
        #pragma unroll
        for (int ks = 0; ks < 2; ++ks){
            short8v b_hi, b_lo;
            #pragma unroll
            for (int j = 0; j < 8; ++j){
                float v = wp[ks * 32 + j];
                short h = bf16t(v);
                b_hi[j] = h;
                b_lo[j] = bf16t(v - bf16tof(h));
            }
            acc[nt] = __builtin_amdgcn_mfma_f32_16x16x32_bf16(a_hi[ks], b_hi, acc[nt], 0, 0, 0);
            acc[nt] = __builtin_amdgcn_mfma_f32_16x16x32_bf16(a_hi[ks], b_lo, acc[nt], 0, 0, 0);
            acc[nt] = __builtin_amdgcn_mfma_f32_16x16x32_bf16(a_lo[ks], b_hi, acc[nt], 0, 0, 0);
        }
    }

    float bcv[3];
    #pragma unroll
    for (int nt = 0; nt < 3; ++nt){
        int f = nt * 16 + r0;
        bcv[nt] = (f < 40) ? bc[f] : 0.f;
    }

    #pragma unroll
    for (int q = 0; q < 4; ++q){
        int node = nb + rg * 4 + q;
        float l0 = acc[0][q] + bcv[0];
        float l1 = acc[1][q] + bcv[1];
        float l2 = (32 + r0 < 40) ? acc[2][q] + bcv[2] : -INFINITY;
        float m = fmaxf(l0, fmaxf(l1, l2));
        #pragma unroll
        for (int off = 8; off; off >>= 1) m = fmaxf(m, __shfl_xor(m, off));
        float s = __expf(l0 - m) + __expf(l1 - m) + ((32 + r0 < 40) ? __expf(l2 - m) : 0.f);
        #pragma unroll
        for (int off = 8; off; off >>= 1) s += __shfl_xor(s, off);
        float lse = m + __logf(s);
        if (node < n){
            out[(size_t)node * 40 + r0]      = l0 - lse;
            out[(size_t)node * 40 + 16 + r0] = l1 - lse;
            if (32 + r0 < 40) out[(size_t)node * 40 + 32 + r0] = l2 - lse;
        }
    }
}

extern "C" void kernel_launch(void* const* d_in, const int* in_sizes, int n_in,
                              void* d_out, int out_size, void* d_ws, size_t ws_size,
                              hipStream_t stream){
    const float* x     = (const float*)d_in[0];
    const int*   ei    = (const int*)  d_in[1];
    const float* W1    = (const float*)d_in[2];
    const float* b1    = (const float*)d_in[3];
    const float* att1  = (const float*)d_in[4];
    const float* bias1 = (const float*)d_in[5];
    const float* W2    = (const float*)d_in[6];
    const float* b2    = (const float*)d_in[7];
    const float* att2  = (const float*)d_in[8];
    const float* bias2 = (const float*)d_in[9];
    const float* Wp1   = (const float*)d_in[10];
    const float* bp1   = (const float*)d_in[11];
    const float* Wp2   = (const float*)d_in[12];
    const float* bp2   = (const float*)d_in[13];
    float* out = (float*)d_out;

    // workspace carve (float offsets; ~26.3 MB; 16B-aligned blocks)
    float*    base     = (float*)d_ws;
    float*    g        = base;                          // 3,200,000 f
    __half*   hh       = (__half*)(base + 3200000);     // NN*64 halves
    unsigned* part     = (unsigned*)(base + 4800000);   // 800,000
    int*      csr      = (int*)(base + 5600000);        // 800,000
    int*      counts   = (int*)(base + 6400000);        // 12,544 (NBUK*NPB)
    int*      rowstart = (int*)(base + 6413200);        // 50,001 (+pad)
    float*    ad       = base + 6463208;                // 50,000
    float*    as_      = base + 6513208;                // 50,000
    float*    Wc       = base + 6563208;                // 2,560
    float*    bc       = base + 6565768;                // 40 (+pad)

    const int* srcv = ei;
    const int* dstv = ei + NE;

    // fused front: lin1 | cntA | wcomb
    k_fuse0 <<<GB + NPB + 1, 256, 0, stream>>>(x, W1, b1, att1, hh, ad, as_,
                                               dstv, counts,
                                               Wp1, bp1, Wp2, bp2, Wc, bc);
    k_partC <<<NPB, 256, 0, stream>>>(srcv, dstv, counts, part);
    k_buildD<<<NBUK, 256, 0, stream>>>(part, counts, rowstart, csr);

    int nb = (NN + 3) / 4;     // 1 node per wave (k_agg)
    k_agg     <<<nb, 256, 0, stream>>>(hh, ad, as_, rowstart, csr, bias1, g, NN);
    k_lin_mfma<<<GB, 256, 0, stream>>>(g, W2, b2, att2, hh, ad, as_, NN);
    k_agg     <<<nb, 256, 0, stream>>>(hh, ad, as_, rowstart, csr, bias2, g, NN);
    k_mlp_mfma<<<GB, 256, 0, stream>>>(g, Wc, bc, out, NN);
}

// Round 13
// 143.822 us; speedup vs baseline: 1.0141x; 1.0141x over previous
//
#include <hip/hip_runtime.h>
#include <hip/hip_fp16.h>
#include <math.h>

#define NN 50000
#define NE 800000
#define NEG 0.2f

#define NPB 128            // partition blocks
#define CHK 6250           // NE / NPB
#define NBUK 98            // bucket = dst >> 9  (512 dst per bucket)
#define LCAP 10240         // per-bucket LDS capacity
#define GB 782             // lin blocks: ceil(NN/64)

typedef __attribute__((ext_vector_type(8))) short short8v;  // 8 bf16 (4 VGPRs)
typedef __attribute__((ext_vector_type(4))) float f32x4;    // MFMA C/D frag

__device__ __forceinline__ float lrelu(float x){ return x > 0.f ? x : NEG * x; }

__device__ __forceinline__ short bf16t(float x){ return (short)(__float_as_uint(x) >> 16); }
__device__ __forceinline__ float bf16tof(short s){
    return __uint_as_float(((unsigned)(unsigned short)s) << 16);
}

// ---------- MFMA linear body: H(fp16) = X@W^T + b, plus attention scalars ----------
__device__ __forceinline__ void lin_body(int blk, int tid,
                                         const float* __restrict__ X,
                                         const float* __restrict__ W,
                                         const float* __restrict__ b,
                                         const float* __restrict__ att,
                                         __half* __restrict__ Hh,
                                         float* __restrict__ ad,
                                         float* __restrict__ as_, int n){
    int lane = tid & 63, wid = tid >> 6;
    int nb = blk * 64 + wid * 16;
    if (nb >= n) return;
    int r0 = lane & 15, rg = lane >> 4;

    short8v a_hi[2], a_lo[2];
    int arow = nb + r0; if (arow >= n) arow = n - 1;
    const float* xp = X + (size_t)arow * 64 + rg * 8;
    #pragma unroll
    for (int ks = 0; ks < 2; ++ks){
        #pragma unroll
        for (int j = 0; j < 8; ++j){
            float v = xp[ks * 32 + j];
            short h = bf16t(v);
            a_hi[ks][j] = h;
            a_lo[ks][j] = bf16t(v - bf16tof(h));
        }
    }

    f32x4 acc[4] = {{0,0,0,0},{0,0,0,0},{0,0,0,0},{0,0,0,0}};
    #pragma unroll
    for (int nt = 0; nt < 4; ++nt){
        const float* wp = W + (size_t)(nt * 16 + r0) * 64 + rg * 8;
        #pragma unroll
        for (int ks = 0; ks < 2; ++ks){
            short8v b_hi, b_lo;
            #pragma unroll
            for (int j = 0; j < 8; ++j){
                float v = wp[ks * 32 + j];
                short h = bf16t(v);
                b_hi[j] = h;
                b_lo[j] = bf16t(v - bf16tof(h));
            }
            acc[nt] = __builtin_amdgcn_mfma_f32_16x16x32_bf16(a_hi[ks], b_hi, acc[nt], 0, 0, 0);
            acc[nt] = __builtin_amdgcn_mfma_f32_16x16x32_bf16(a_hi[ks], b_lo, acc[nt], 0, 0, 0);
            acc[nt] = __builtin_amdgcn_mfma_f32_16x16x32_bf16(a_lo[ks], b_hi, acc[nt], 0, 0, 0);
        }
    }

    #pragma unroll
    for (int nt = 0; nt < 4; ++nt){
        float bb = b[nt * 16 + r0];
        #pragma unroll
        for (int q = 0; q < 4; ++q){
            int node = nb + rg * 4 + q;
            float v = acc[nt][q] + bb;
            acc[nt][q] = v;
            if (node < n) Hh[(size_t)node * 64 + nt * 16 + r0] = __float2half(v);
        }
    }

    float attd[4], atts[4];
    #pragma unroll
    for (int nt = 0; nt < 4; ++nt){
        attd[nt] = att[nt * 16 + r0];
        atts[nt] = att[64 + nt * 16 + r0];
    }
    #pragma unroll
    for (int q = 0; q < 4; ++q){
        float pd = 0.f, ps = 0.f;
        #pragma unroll
        for (int nt = 0; nt < 4; ++nt){
            pd = fmaf(attd[nt], acc[nt][q], pd);
            ps = fmaf(atts[nt], acc[nt][q], ps);
        }
        #pragma unroll
        for (int off = 8; off; off >>= 1){
            pd += __shfl_xor(pd, off);
            ps += __shfl_xor(ps, off);
        }
        int node = nb + rg * 4 + q;
        if (r0 == 0 && node < n){ ad[node] = pd; as_[node] = ps; }
    }
}

// ---------- fused front: lin1 [0,GB) | cntA [GB,GB+NPB) | wcomb [GB+NPB] ----------
__global__ __launch_bounds__(256) void k_fuse0(const float* __restrict__ X,
                                               const float* __restrict__ W1,
                                               const float* __restrict__ b1,
                                               const float* __restrict__ att1,
                                               __half* __restrict__ Hh,
                                               float* __restrict__ ad,
                                               float* __restrict__ as_,
                                               const int* __restrict__ dst,
                                               int* __restrict__ counts,
                                               const float* __restrict__ Wp1,
                                               const float* __restrict__ bp1,
                                               const float* __restrict__ Wp2,
                                               const float* __restrict__ bp2,
                                               float* __restrict__ Wc,
                                               float* __restrict__ bc){
    __shared__ int c[NBUK];
    int tid = threadIdx.x, blk = blockIdx.x;
    if (blk < GB){
        lin_body(blk, tid, X, W1, b1, att1, Hh, ad, as_, NN);
    } else if (blk < GB + NPB){
        int cb = blk - GB;
        for (int i = tid; i < NBUK; i += 256) c[i] = 0;
        __syncthreads();
        int beg = cb * CHK, end = min(beg + CHK, NE);
        for (int i = beg + tid; i < end; i += 256) atomicAdd(&c[dst[i] >> 9], 1);
        __syncthreads();
        for (int i = tid; i < NBUK; i += 256) counts[i * NPB + cb] = c[i];
    } else {
        for (int idx = tid; idx < 2560; idx += 256){
            int cc = idx >> 6, k = idx & 63;
            float s = 0.f;
            #pragma unroll 8
            for (int j = 0; j < 64; ++j) s = fmaf(Wp2[cc * 64 + j], Wp1[j * 64 + k], s);
            Wc[idx] = s;
        }
        if (tid < 40){
            float s = bp2[tid];
            for (int j = 0; j < 64; ++j) s = fmaf(Wp2[tid * 64 + j], bp1[j], s);
            bc[tid] = s;
        }
    }
}

// small in-block scan of totsh[98] -> bb (exclusive); threads 0..127 participate
__device__ __forceinline__ void bbase_scan(const int* tot, int* bb, int* wsum, int tid){
    int lane = tid & 63, w2 = tid >> 6;
    int vv = 0, incl = 0;
    if (tid < 128){
        vv = (tid < NBUK) ? tot[tid] : 0;
        incl = vv;
        #pragma unroll
        for (int off = 1; off < 64; off <<= 1){
            int t = __shfl_up(incl, off);
            if (lane >= off) incl += t;
        }
        if (lane == 63) wsum[w2] = incl;
    }
    __syncthreads();
    if (tid < NBUK) bb[tid] = incl - vv + (w2 ? wsum[0] : 0);
    __syncthreads();
}

// ---------- C: partition; per-block offsets computed in-block from raw counts ----------
__global__ __launch_bounds__(256) void k_partC(const int* __restrict__ src,
                                               const int* __restrict__ dst,
                                               const int* __restrict__ counts,
                                               unsigned* __restrict__ part){
    __shared__ int lcur[NBUK];
    __shared__ int totsh[NBUK];
    __shared__ int bb[NBUK];
    __shared__ int wsum[2];
    int tid = threadIdx.x, blk = blockIdx.x;
    if (tid < NBUK){
        const int* row = counts + tid * NPB;
        int pre = 0, tt = 0;
        for (int i = 0; i < NPB; ++i){
            int cc = row[i];
            tt += cc;
            pre += (i < blk) ? cc : 0;
        }
        totsh[tid] = tt;
        lcur[tid] = pre;
    }
    __syncthreads();
    bbase_scan(totsh, bb, wsum, tid);
    if (tid < NBUK) lcur[tid] += bb[tid];
    __syncthreads();
    int beg = blk * CHK, end = min(beg + CHK, NE);
    for (int i = beg + tid; i < end; i += 256){
        int d = dst[i];
        int pos = atomicAdd(&lcur[d >> 9], 1);
        part[pos] = ((unsigned)(d & 511) << 16) | (unsigned)src[i];
    }
}

// ---------- D: per-bucket CSR build; bases recomputed in-block ----------
__global__ __launch_bounds__(256) void k_buildD(const unsigned* __restrict__ part,
                                                const int* __restrict__ counts,
                                                int* __restrict__ rowstart,
                                                int* __restrict__ csr){
    __shared__ int hist[512], cur[512];
    __shared__ int csrbuf[LCAP];
    __shared__ int swave[4];
    __shared__ int totsh[NBUK];
    __shared__ int bb[NBUK];
    __shared__ int wsum2[2];
    int tid = threadIdx.x, lane = tid & 63, wid = tid >> 6;
    int b = blockIdx.x;
    if (tid < NBUK){
        const int* row = counts + tid * NPB;
        int tt = 0;
        for (int i = 0; i < NPB; ++i) tt += row[i];
        totsh[tid] = tt;
    }
    __syncthreads();
    bbase_scan(totsh, bb, wsum2, tid);
    int ebeg = bb[b], cnt = totsh[b];

    for (int i = tid; i < 512; i += 256) hist[i] = 0;
    __syncthreads();
    for (int i = tid; i < cnt; i += 256) atomicAdd(&hist[part[ebeg + i] >> 16], 1);
    __syncthreads();

    int h0 = hist[2 * tid], h1 = hist[2 * tid + 1];
    int v = h0 + h1, incl = v;
    #pragma unroll
    for (int off = 1; off < 64; off <<= 1){
        int t = __shfl_up(incl, off);
        if (lane >= off) incl += t;
    }
    if (lane == 63) swave[wid] = incl;
    __syncthreads();
    int woff = 0;
    #pragma unroll
    for (int w = 0; w < 4; ++w) if (w < wid) woff += swave[w];
    int e0 = woff + incl - v;
    int e1 = e0 + h0;
    cur[2 * tid] = e0; cur[2 * tid + 1] = e1;
    int gi = b * 512 + 2 * tid;
    if (gi     <= NN) rowstart[gi]     = ebeg + e0;
    if (gi + 1 <= NN) rowstart[gi + 1] = ebeg + e1;
    __syncthreads();

    for (int i = tid; i < cnt; i += 256){
        unsigned u = part[ebeg + i];
        int lp = atomicAdd(&cur[u >> 16], 1);
        if (lp < LCAP) csrbuf[lp] = (int)(u & 0xFFFFu);
    }
    __syncthreads();
    int m = min(cnt, LCAP);
    for (int i = tid; i < m; i += 256) csr[ebeg + i] = csrbuf[i];
}

// ---------- plain lin kernel (layer 2) ----------
__global__ __launch_bounds__(256) void k_lin_mfma(const float* __restrict__ X,
                                                  const float* __restrict__ W,
                                                  const float* __restrict__ b,
                                                  const float* __restrict__ att,
                                                  __half* __restrict__ Hh,
                                                  float* __restrict__ ad,
                                                  float* __restrict__ as_, int n){
    lin_body(blockIdx.x, threadIdx.x, X, W, b, att, Hh, ad, as_, n);
}

// ---------- GAT aggregation: TWO nodes per wave, LDS-staged s/e, joint 16-deep gathers ----------
// wave wid handles nodes blk*8+wid (A) and blk*8+4+wid (B). Phase-1 chains for A and B
// overlap; phase-2 issues 8 gathers for each (16 in flight). e=0 slots -> no-op fma.
__global__ __launch_bounds__(256) void k_agg(const __half2* __restrict__ H2,
                                             const float* __restrict__ ad,
                                             const float* __restrict__ as_,
                                             const int* __restrict__ rowstart,
                                             const int* __restrict__ csr,
                                             const float2* __restrict__ bias2,
                                             float2* __restrict__ OUT2, int n){
    __shared__ float e_sh[8][64];
    __shared__ int   s_sh[8][64];
    int tid = threadIdx.x, lane = tid & 63, wid = tid >> 6;
    int nodeA = blockIdx.x * 8 + wid;
    int nodeB = nodeA + 4;
    if (nodeA >= n) return;
    bool hasB = (nodeB < n);
    int begA = rowstart[nodeA], endA = rowstart[nodeA + 1];
    int begB = hasB ? rowstart[nodeB] : 0, endB = hasB ? rowstart[nodeB + 1] : 0;
    float adA = ad[nodeA];
    float adB = hasB ? ad[nodeB] : 0.f;
    int half = lane >> 5, hl = lane & 31;

    float axA = 0.f, ayA = 0.f, dA = 0.f;
    float axB = 0.f, ayB = 0.f, dB = 0.f;
    int ncA = (endA - begA + 63) >> 6, ncB = (endB - begB + 63) >> 6;
    int nchunk = max(ncA, ncB);

    for (int c = 0; c < nchunk; ++c){
        int kA = begA + (c << 6) + lane;
        int kB = begB + (c << 6) + lane;
        bool vA = (kA < endA), vB = hasB && (kB < endB);
        int sA = vA ? csr[kA] : 0;
        int sB = vB ? csr[kB] : 0;
        float eA = vA ? __expf(lrelu(adA + as_[sA])) : 0.f;
        float eB = vB ? __expf(lrelu(adB + as_[sB])) : 0.f;
        e_sh[wid][lane] = eA;     s_sh[wid][lane] = sA;
        e_sh[wid + 4][lane] = eB; s_sh[wid + 4][lane] = sB;
        dA += eA;                 // per-lane accumulation; reduced once at the end
        dB += eB;
        int cA = min(64, max(0, endA - (begA + (c << 6))));
        int cB = min(64, max(0, endB - (begB + (c << 6))));
        int cmax = max(cA, cB);
        for (int j = 0; j < cmax; j += 16){
            float2 fA[8], fB[8]; float eeA[8], eeB[8];
            #pragma unroll
            for (int t = 0; t < 8; ++t){
                int idx = j + 2 * t + half;            // <= 63 always
                int ssA = s_sh[wid][idx];     eeA[t] = e_sh[wid][idx];
                int ssB = s_sh[wid + 4][idx]; eeB[t] = e_sh[wid + 4][idx];
                fA[t] = __half22float2(H2[(size_t)ssA * 32 + hl]);
                fB[t] = __half22float2(H2[(size_t)ssB * 32 + hl]);
            }
            #pragma unroll
            for (int t = 0; t < 8; ++t){
                axA = fmaf(eeA[t], fA[t].x, axA); ayA = fmaf(eeA[t], fA[t].y, ayA);
                axB = fmaf(eeB[t], fB[t].x, axB); ayB = fmaf(eeB[t], fB[t].y, ayB);
            }
        }
    }
    // final reductions: denom over all 64 lanes; acc over the two halves
    #pragma unroll
    for (int off = 32; off; off >>= 1){ dA += __shfl_xor(dA, off); dB += __shfl_xor(dB, off); }
    axA += __shfl_xor(axA, 32); ayA += __shfl_xor(ayA, 32);
    axB += __shfl_xor(axB, 32); ayB += __shfl_xor(ayB, 32);
    if (half == 0){
        float2 bb = bias2[hl];
        float invA = 1.f / (dA + 1e-16f);
        float2 oA;
        oA.x = fmaxf(fmaf(axA, invA, bb.x), 0.f);
        oA.y = fmaxf(fmaf(ayA, invA, bb.y), 0.f);
        OUT2[(size_t)nodeA * 32 + hl] = oA;
        if (hasB){
            float invB = 1.f / (dB + 1e-16f);
            float2 oB;
            oB.x = fmaxf(fmaf(axB, invB, bb.x), 0.f);
            oB.y = fmaxf(fmaf(ayB, invB, bb.y), 0.f);
            OUT2[(size_t)nodeB * 32 + hl] = oB;
        }
    }
}

// ---------- MFMA MLP: out = log_softmax(G@Wc^T + bc) ----------
__global__ __launch_bounds__(256) void k_mlp_mfma(const float* __restrict__ G,
                                                  const float* __restrict__ Wc,
                                                  const float* __restrict__ bc,
                                                  float* __restrict__ out, int n){
    int lane = threadIdx.x & 63, wid = threadIdx.x >> 6;
    int nb = blockIdx.x * 64 + wid * 16;
    if (nb >= n) return;
    int r0 = lane & 15, rg = lane >> 4;

    short8v a_hi[2], a_lo[2];
    int arow = nb + r0; if (arow >= n) arow = n - 1;
    const float* gp = G + (size_t)arow * 64 + rg * 8;
    #pragma unroll
    for (int ks = 0; ks < 2; ++ks){
        #pragma unroll
        for (int j = 0; j < 8; ++j){
            float v = gp[ks * 32 + j];
            short h = bf16t(v);
            a_hi[ks][j] = h;
            a_lo[ks][j] = bf16t(v - bf16tof(h));
        }
    }

    f32x4 acc[3] = {{0,0,0,0},{0,0,0,0},{0,0,0,0}};
    #pragma unroll
    for (int nt = 0; nt < 3; ++nt){
        int f = nt * 16 + r0;
        int fr = (f < 40) ? f : 39;
        const float* wp = Wc + (size_t)fr * 64 + rg * 8;
        #pragma unroll
        for (int ks = 0; ks < 2; ++ks){
            short8v b_hi, b_lo;
            #pragma unroll
            for (int j = 0; j < 8; ++j){
                float v = wp[ks * 32 + j];
                short h = bf16t(v);
                b_hi[j] = h;
                b_lo[j] = bf16t(v - bf16tof(h));
            }
            acc[nt] = __builtin_amdgcn_mfma_f32_16x16x32_bf16(a_hi[ks], b_hi, acc[nt], 0, 0, 0);
            acc[nt] = __builtin_amdgcn_mfma_f32_16x16x32_bf16(a_hi[ks], b_lo, acc[nt], 0, 0, 0);
            acc[nt] = __builtin_amdgcn_mfma_f32_16x16x32_bf16(a_lo[ks], b_hi, acc[nt], 0, 0, 0);
        }
    }

    float bcv[3];
    #pragma unroll
    for (int nt = 0; nt < 3; ++nt){
        int f = nt * 16 + r0;
        bcv[nt] = (f < 40) ? bc[f] : 0.f;
    }

    #pragma unroll
    for (int q = 0; q < 4; ++q){
        int node = nb + rg * 4 + q;
        float l0 = acc[0][q] + bcv[0];
        float l1 = acc[1][q] + bcv[1];
        float l2 = (32 + r0 < 40) ? acc[2][q] + bcv[2] : -INFINITY;
        float m = fmaxf(l0, fmaxf(l1, l2));
        #pragma unroll
        for (int off = 8; off; off >>= 1) m = fmaxf(m, __shfl_xor(m, off));
        float s = __expf(l0 - m) + __expf(l1 - m) + ((32 + r0 < 40) ? __expf(l2 - m) : 0.f);
        #pragma unroll
        for (int off = 8; off; off >>= 1) s += __shfl_xor(s, off);
        float lse = m + __logf(s);
        if (node < n){
            out[(size_t)node * 40 + r0]      = l0 - lse;
            out[(size_t)node * 40 + 16 + r0] = l1 - lse;
            if (32 + r0 < 40) out[(size_t)node * 40 + 32 + r0] = l2 - lse;
        }
    }
}

extern "C" void kernel_launch(void* const* d_in, const int* in_sizes, int n_in,
                              void* d_out, int out_size, void* d_ws, size_t ws_size,
                              hipStream_t stream){
    const float* x     = (const float*)d_in[0];
    const int*   ei    = (const int*)  d_in[1];
    const float* W1    = (const float*)d_in[2];
    const float* b1    = (const float*)d_in[3];
    const float* att1  = (const float*)d_in[4];
    const float* bias1 = (const float*)d_in[5];
    const float* W2    = (const float*)d_in[6];
    const float* b2    = (const float*)d_in[7];
    const float* att2  = (const float*)d_in[8];
    const float* bias2 = (const float*)d_in[9];
    const float* Wp1   = (const float*)d_in[10];
    const float* bp1   = (const float*)d_in[11];
    const float* Wp2   = (const float*)d_in[12];
    const float* bp2   = (const float*)d_in[13];
    float* out = (float*)d_out;

    // workspace carve (float offsets; ~26.3 MB; 16B-aligned blocks)
    float*    base     = (float*)d_ws;
    float*    g        = base;                          // 3,200,000 f
    __half*   hh       = (__half*)(base + 3200000);     // NN*64 halves
    unsigned* part     = (unsigned*)(base + 4800000);   // 800,000
    int*      csr      = (int*)(base + 5600000);        // 800,000
    int*      counts   = (int*)(base + 6400000);        // 12,544 (NBUK*NPB)
    int*      rowstart = (int*)(base + 6413200);        // 50,001 (+pad)
    float*    ad       = base + 6463208;                // 50,000
    float*    as_      = base + 6513208;                // 50,000
    float*    Wc       = base + 6563208;                // 2,560
    float*    bc       = base + 6565768;                // 40 (+pad)

    const int* srcv = ei;
    const int* dstv = ei + NE;

    // fused front: lin1 | cntA | wcomb
    k_fuse0 <<<GB + NPB + 1, 256, 0, stream>>>(x, W1, b1, att1, hh, ad, as_,
                                               dstv, counts,
                                               Wp1, bp1, Wp2, bp2, Wc, bc);
    k_partC <<<NPB, 256, 0, stream>>>(srcv, dstv, counts, part);
    k_buildD<<<NBUK, 256, 0, stream>>>(part, counts, rowstart, csr);

    int nb = (NN + 7) / 8;     // 2 nodes per wave (k_agg)
    k_agg     <<<nb, 256, 0, stream>>>((const __half2*)hh, ad, as_, rowstart, csr,
                                       (const float2*)bias1, (float2*)g, NN);
    k_lin_mfma<<<GB, 256, 0, stream>>>(g, W2, b2, att2, hh, ad, as_, NN);
    k_agg     <<<nb, 256, 0, stream>>>((const __half2*)hh, ad, as_, rowstart, csr,
                                       (const float2*)bias2, (float2*)g, NN);
    k_mlp_mfma<<<GB, 256, 0, stream>>>(g, Wc, bc, out, NN);
}

// Round 14
// 139.723 us; speedup vs baseline: 1.0438x; 1.0293x over previous
//
#include <hip/hip_runtime.h>
#include <hip/hip_fp16.h>
#include <math.h>

#define NN 50000
#define NE 800000
#define NEG 0.2f

#define NPB 128            // partition blocks
#define CHK 6250           // NE / NPB
#define NBUK 98            // bucket = dst >> 9  (512 dst per bucket)
#define LCAP 10240         // per-bucket LDS capacity
#define GB 782             // lin blocks: ceil(NN/64)

typedef __attribute__((ext_vector_type(8))) short short8v;  // 8 bf16 (4 VGPRs)
typedef __attribute__((ext_vector_type(4))) float f32x4;    // MFMA C/D frag

__device__ __forceinline__ float lrelu(float x){ return x > 0.f ? x : NEG * x; }

__device__ __forceinline__ short bf16t(float x){ return (short)(__float_as_uint(x) >> 16); }
__device__ __forceinline__ float bf16tof(short s){
    return __uint_as_float(((unsigned)(unsigned short)s) << 16);
}

// ---------- MFMA linear body (float input): H(fp16) = X@W^T + b, + att scalars ----------
__device__ __forceinline__ void lin_body(int blk, int tid,
                                         const float* __restrict__ X,
                                         const float* __restrict__ W,
                                         const float* __restrict__ b,
                                         const float* __restrict__ att,
                                         __half* __restrict__ Hh,
                                         float* __restrict__ ad,
                                         float* __restrict__ as_, int n){
    int lane = tid & 63, wid = tid >> 6;
    int nb = blk * 64 + wid * 16;
    if (nb >= n) return;
    int r0 = lane & 15, rg = lane >> 4;

    short8v a_hi[2], a_lo[2];
    int arow = nb + r0; if (arow >= n) arow = n - 1;
    const float* xp = X + (size_t)arow * 64 + rg * 8;
    #pragma unroll
    for (int ks = 0; ks < 2; ++ks){
        #pragma unroll
        for (int j = 0; j < 8; ++j){
            float v = xp[ks * 32 + j];
            short h = bf16t(v);
            a_hi[ks][j] = h;
            a_lo[ks][j] = bf16t(v - bf16tof(h));
        }
    }

    f32x4 acc[4] = {{0,0,0,0},{0,0,0,0},{0,0,0,0},{0,0,0,0}};
    #pragma unroll
    for (int nt = 0; nt < 4; ++nt){
        const float* wp = W + (size_t)(nt * 16 + r0) * 64 + rg * 8;
        #pragma unroll
        for (int ks = 0; ks < 2; ++ks){
            short8v b_hi, b_lo;
            #pragma unroll
            for (int j = 0; j < 8; ++j){
                float v = wp[ks * 32 + j];
                short h = bf16t(v);
                b_hi[j] = h;
                b_lo[j] = bf16t(v - bf16tof(h));
            }
            acc[nt] = __builtin_amdgcn_mfma_f32_16x16x32_bf16(a_hi[ks], b_hi, acc[nt], 0, 0, 0);
            acc[nt] = __builtin_amdgcn_mfma_f32_16x16x32_bf16(a_hi[ks], b_lo, acc[nt], 0, 0, 0);
            acc[nt] = __builtin_amdgcn_mfma_f32_16x16x32_bf16(a_lo[ks], b_hi, acc[nt], 0, 0, 0);
        }
    }

    #pragma unroll
    for (int nt = 0; nt < 4; ++nt){
        float bb = b[nt * 16 + r0];
        #pragma unroll
        for (int q = 0; q < 4; ++q){
            int node = nb + rg * 4 + q;
            float v = acc[nt][q] + bb;
            acc[nt][q] = v;
            if (node < n) Hh[(size_t)node * 64 + nt * 16 + r0] = __float2half(v);
        }
    }

    float attd[4], atts[4];
    #pragma unroll
    for (int nt = 0; nt < 4; ++nt){
        attd[nt] = att[nt * 16 + r0];
        atts[nt] = att[64 + nt * 16 + r0];
    }
    #pragma unroll
    for (int q = 0; q < 4; ++q){
        float pd = 0.f, ps = 0.f;
        #pragma unroll
        for (int nt = 0; nt < 4; ++nt){
            pd = fmaf(attd[nt], acc[nt][q], pd);
            ps = fmaf(atts[nt], acc[nt][q], ps);
        }
        #pragma unroll
        for (int off = 8; off; off >>= 1){
            pd += __shfl_xor(pd, off);
            ps += __shfl_xor(ps, off);
        }
        int node = nb + rg * 4 + q;
        if (r0 == 0 && node < n){ ad[node] = pd; as_[node] = ps; }
    }
}

// ---------- fused front: lin1 [0,GB) | cntA [GB,GB+NPB) | wcomb [GB+NPB] ----------
__global__ __launch_bounds__(256) void k_fuse0(const float* __restrict__ X,
                                               const float* __restrict__ W1,
                                               const float* __restrict__ b1,
                                               const float* __restrict__ att1,
                                               __half* __restrict__ Hh,
                                               float* __restrict__ ad,
                                               float* __restrict__ as_,
                                               const int* __restrict__ dst,
                                               int* __restrict__ counts,
                                               const float* __restrict__ Wp1,
                                               const float* __restrict__ bp1,
                                               const float* __restrict__ Wp2,
                                               const float* __restrict__ bp2,
                                               float* __restrict__ Wc,
                                               float* __restrict__ bc){
    __shared__ int c[NBUK];
    int tid = threadIdx.x, blk = blockIdx.x;
    if (blk < GB){
        lin_body(blk, tid, X, W1, b1, att1, Hh, ad, as_, NN);
    } else if (blk < GB + NPB){
        int cb = blk - GB;
        for (int i = tid; i < NBUK; i += 256) c[i] = 0;
        __syncthreads();
        int beg = cb * CHK, end = min(beg + CHK, NE);
        for (int i = beg + tid; i < end; i += 256) atomicAdd(&c[dst[i] >> 9], 1);
        __syncthreads();
        for (int i = tid; i < NBUK; i += 256) counts[i * NPB + cb] = c[i];
    } else {
        for (int idx = tid; idx < 2560; idx += 256){
            int cc = idx >> 6, k = idx & 63;
            float s = 0.f;
            #pragma unroll 8
            for (int j = 0; j < 64; ++j) s = fmaf(Wp2[cc * 64 + j], Wp1[j * 64 + k], s);
            Wc[idx] = s;
        }
        if (tid < 40){
            float s = bp2[tid];
            for (int j = 0; j < 64; ++j) s = fmaf(Wp2[tid * 64 + j], bp1[j], s);
            bc[tid] = s;
        }
    }
}

// small in-block scan of totsh[98] -> bb (exclusive); threads 0..127 participate
__device__ __forceinline__ void bbase_scan(const int* tot, int* bb, int* wsum, int tid){
    int lane = tid & 63, w2 = tid >> 6;
    int vv = 0, incl = 0;
    if (tid < 128){
        vv = (tid < NBUK) ? tot[tid] : 0;
        incl = vv;
        #pragma unroll
        for (int off = 1; off < 64; off <<= 1){
            int t = __shfl_up(incl, off);
            if (lane >= off) incl += t;
        }
        if (lane == 63) wsum[w2] = incl;
    }
    __syncthreads();
    if (tid < NBUK) bb[tid] = incl - vv + (w2 ? wsum[0] : 0);
    __syncthreads();
}

// ---------- C: partition; per-block offsets computed in-block from raw counts ----------
__global__ __launch_bounds__(256) void k_partC(const int* __restrict__ src,
                                               const int* __restrict__ dst,
                                               const int* __restrict__ counts,
                                               unsigned* __restrict__ part){
    __shared__ int lcur[NBUK];
    __shared__ int totsh[NBUK];
    __shared__ int bb[NBUK];
    __shared__ int wsum[2];
    int tid = threadIdx.x, blk = blockIdx.x;
    if (tid < NBUK){
        const int* row = counts + tid * NPB;
        int pre = 0, tt = 0;
        for (int i = 0; i < NPB; ++i){
            int cc = row[i];
            tt += cc;
            pre += (i < blk) ? cc : 0;
        }
        totsh[tid] = tt;
        lcur[tid] = pre;
    }
    __syncthreads();
    bbase_scan(totsh, bb, wsum, tid);
    if (tid < NBUK) lcur[tid] += bb[tid];
    __syncthreads();
    int beg = blk * CHK, end = min(beg + CHK, NE);
    for (int i = beg + tid; i < end; i += 256){
        int d = dst[i];
        int pos = atomicAdd(&lcur[d >> 9], 1);
        part[pos] = ((unsigned)(d & 511) << 16) | (unsigned)src[i];
    }
}

// ---------- D: per-bucket CSR build; bases recomputed in-block ----------
__global__ __launch_bounds__(256) void k_buildD(const unsigned* __restrict__ part,
                                                const int* __restrict__ counts,
                                                int* __restrict__ rowstart,
                                                int* __restrict__ csr){
    __shared__ int hist[512], cur[512];
    __shared__ int csrbuf[LCAP];
    __shared__ int swave[4];
    __shared__ int totsh[NBUK];
    __shared__ int bb[NBUK];
    __shared__ int wsum2[2];
    int tid = threadIdx.x, lane = tid & 63, wid = tid >> 6;
    int b = blockIdx.x;
    if (tid < NBUK){
        const int* row = counts + tid * NPB;
        int tt = 0;
        for (int i = 0; i < NPB; ++i) tt += row[i];
        totsh[tid] = tt;
    }
    __syncthreads();
    bbase_scan(totsh, bb, wsum2, tid);
    int ebeg = bb[b], cnt = totsh[b];

    for (int i = tid; i < 512; i += 256) hist[i] = 0;
    __syncthreads();
    for (int i = tid; i < cnt; i += 256) atomicAdd(&hist[part[ebeg + i] >> 16], 1);
    __syncthreads();

    int h0 = hist[2 * tid], h1 = hist[2 * tid + 1];
    int v = h0 + h1, incl = v;
    #pragma unroll
    for (int off = 1; off < 64; off <<= 1){
        int t = __shfl_up(incl, off);
        if (lane >= off) incl += t;
    }
    if (lane == 63) swave[wid] = incl;
    __syncthreads();
    int woff = 0;
    #pragma unroll
    for (int w = 0; w < 4; ++w) if (w < wid) woff += swave[w];
    int e0 = woff + incl - v;
    int e1 = e0 + h0;
    cur[2 * tid] = e0; cur[2 * tid + 1] = e1;
    int gi = b * 512 + 2 * tid;
    if (gi     <= NN) rowstart[gi]     = ebeg + e0;
    if (gi + 1 <= NN) rowstart[gi + 1] = ebeg + e1;
    __syncthreads();

    for (int i = tid; i < cnt; i += 256){
        unsigned u = part[ebeg + i];
        int lp = atomicAdd(&cur[u >> 16], 1);
        if (lp < LCAP) csrbuf[lp] = (int)(u & 0xFFFFu);
    }
    __syncthreads();
    int m = min(cnt, LCAP);
    for (int i = tid; i < m; i += 256) csr[ebeg + i] = csrbuf[i];
}

// ---------- lin kernel (layer 2): fp16 input ----------
__global__ __launch_bounds__(256) void k_lin_mfma_h(const __half* __restrict__ X,
                                                    const float* __restrict__ W,
                                                    const float* __restrict__ b,
                                                    const float* __restrict__ att,
                                                    __half* __restrict__ Hh,
                                                    float* __restrict__ ad,
                                                    float* __restrict__ as_, int n){
    int tid = threadIdx.x;
    int lane = tid & 63, wid = tid >> 6;
    int nb = blockIdx.x * 64 + wid * 16;
    if (nb >= n) return;
    int r0 = lane & 15, rg = lane >> 4;

    short8v a_hi[2], a_lo[2];
    int arow = nb + r0; if (arow >= n) arow = n - 1;
    const __half* xp = X + (size_t)arow * 64 + rg * 8;
    #pragma unroll
    for (int ks = 0; ks < 2; ++ks){
        float4 hv = *(const float4*)(xp + ks * 32);          // 8 halves
        const __half2* h2 = (const __half2*)&hv;
        #pragma unroll
        for (int p = 0; p < 4; ++p){
            float2 f = __half22float2(h2[p]);
            short hx = bf16t(f.x), hy = bf16t(f.y);
            a_hi[ks][2*p]   = hx; a_lo[ks][2*p]   = bf16t(f.x - bf16tof(hx));
            a_hi[ks][2*p+1] = hy; a_lo[ks][2*p+1] = bf16t(f.y - bf16tof(hy));
        }
    }

    f32x4 acc[4] = {{0,0,0,0},{0,0,0,0},{0,0,0,0},{0,0,0,0}};
    #pragma unroll
    for (int nt = 0; nt < 4; ++nt){
        const float* wp = W + (size_t)(nt * 16 + r0) * 64 + rg * 8;
        #pragma unroll
        for (int ks = 0; ks < 2; ++ks){
            short8v b_hi, b_lo;
            #pragma unroll
            for (int j = 0; j < 8; ++j){
                float v = wp[ks * 32 + j];
                short h = bf16t(v);
                b_hi[j] = h;
                b_lo[j] = bf16t(v - bf16tof(h));
            }
            acc[nt] = __builtin_amdgcn_mfma_f32_16x16x32_bf16(a_hi[ks], b_hi, acc[nt], 0, 0, 0);
            acc[nt] = __builtin_amdgcn_mfma_f32_16x16x32_bf16(a_hi[ks], b_lo, acc[nt], 0, 0, 0);
            acc[nt] = __builtin_amdgcn_mfma_f32_16x16x32_bf16(a_lo[ks], b_hi, acc[nt], 0, 0, 0);
        }
    }

    #pragma unroll
    for (int nt = 0; nt < 4; ++nt){
        float bb = b[nt * 16 + r0];
        #pragma unroll
        for (int q = 0; q < 4; ++q){
            int node = nb + rg * 4 + q;
            float v = acc[nt][q] + bb;
            acc[nt][q] = v;
            if (node < n) Hh[(size_t)node * 64 + nt * 16 + r0] = __float2half(v);
        }
    }

    float attd[4], atts[4];
    #pragma unroll
    for (int nt = 0; nt < 4; ++nt){
        attd[nt] = att[nt * 16 + r0];
        atts[nt] = att[64 + nt * 16 + r0];
    }
    #pragma unroll
    for (int q = 0; q < 4; ++q){
        float pd = 0.f, ps = 0.f;
        #pragma unroll
        for (int nt = 0; nt < 4; ++nt){
            pd = fmaf(attd[nt], acc[nt][q], pd);
            ps = fmaf(atts[nt], acc[nt][q], ps);
        }
        #pragma unroll
        for (int off = 8; off; off >>= 1){
            pd += __shfl_xor(pd, off);
            ps += __shfl_xor(ps, off);
        }
        int node = nb + rg * 4 + q;
        if (r0 == 0 && node < n){ ad[node] = pd; as_[node] = ps; }
    }
}

// ---------- GAT aggregation: one wave per node, LDS-staged s/e, 8-deep gathers ----------
// identical structure to the 140.8us best (R11); output now fp16
__global__ __launch_bounds__(256) void k_agg(const __half2* __restrict__ H2,
                                             const float* __restrict__ ad,
                                             const float* __restrict__ as_,
                                             const int* __restrict__ rowstart,
                                             const int* __restrict__ csr,
                                             const float2* __restrict__ bias2,
                                             __half2* __restrict__ OUTh, int n){
    __shared__ float e_sh[4][64];
    __shared__ int   s_sh[4][64];
    int tid = threadIdx.x, lane = tid & 63, wid = tid >> 6;
    int node = blockIdx.x * 4 + wid;
    if (node >= n) return;
    int beg = rowstart[node], end = rowstart[node + 1];
    float adn = ad[node];
    int half = lane >> 5, hl = lane & 31;

    float accx = 0.f, accy = 0.f, denom = 0.f;
    for (int cbeg = beg; cbeg < end; cbeg += 64){
        int k = cbeg + lane;
        bool valid = (k < end);
        int s = valid ? csr[k] : 0;
        float e = valid ? __expf(lrelu(adn + as_[s])) : 0.f;
        e_sh[wid][lane] = e;
        s_sh[wid][lane] = valid ? s : 0;
        float es = e;
        #pragma unroll
        for (int off = 32; off; off >>= 1) es += __shfl_xor(es, off);
        denom += es;
        int cnt = min(64, end - cbeg);
        // 16-edge batches: 8 independent gathers in flight per half-wave lane
        for (int j = 0; j < cnt; j += 16){
            float2 f[8]; float ee[8];
            #pragma unroll
            for (int t = 0; t < 8; ++t){
                int idx = j + 2 * t + half;            // <= 63 always
                int ss = s_sh[wid][idx];
                ee[t] = e_sh[wid][idx];                // 0 beyond cnt -> no-op fma
                f[t] = __half22float2(H2[(size_t)ss * 32 + hl]);
            }
            #pragma unroll
            for (int t = 0; t < 8; ++t){
                accx = fmaf(ee[t], f[t].x, accx);
                accy = fmaf(ee[t], f[t].y, accy);
            }
        }
    }
    accx += __shfl_xor(accx, 32);
    accy += __shfl_xor(accy, 32);
    if (half == 0){
        float2 bb = bias2[hl];
        float inv = 1.f / (denom + 1e-16f);
        float ox = fmaxf(fmaf(accx, inv, bb.x), 0.f);
        float oy = fmaxf(fmaf(accy, inv, bb.y), 0.f);
        OUTh[(size_t)node * 32 + hl] = __floats2half2_rn(ox, oy);
    }
}

// ---------- MFMA MLP: out = log_softmax(G@Wc^T + bc); fp16 input ----------
__global__ __launch_bounds__(256) void k_mlp_mfma(const __half* __restrict__ G,
                                                  const float* __restrict__ Wc,
                                                  const float* __restrict__ bc,
                                                  float* __restrict__ out, int n){
    int lane = threadIdx.x & 63, wid = threadIdx.x >> 6;
    int nb = blockIdx.x * 64 + wid * 16;
    if (nb >= n) return;
    int r0 = lane & 15, rg = lane >> 4;

    short8v a_hi[2], a_lo[2];
    int arow = nb + r0; if (arow >= n) arow = n - 1;
    const __half* gp = G + (size_t)arow * 64 + rg * 8;
    #pragma unroll
    for (int ks = 0; ks < 2; ++ks){
        float4 hv = *(const float4*)(gp + ks * 32);          // 8 halves
        const __half2* h2 = (const __half2*)&hv;
        #pragma unroll
        for (int p = 0; p < 4; ++p){
            float2 f = __half22float2(h2[p]);
            short hx = bf16t(f.x), hy = bf16t(f.y);
            a_hi[ks][2*p]   = hx; a_lo[ks][2*p]   = bf16t(f.x - bf16tof(hx));
            a_hi[ks][2*p+1] = hy; a_lo[ks][2*p+1] = bf16t(f.y - bf16tof(hy));
        }
    }

    f32x4 acc[3] = {{0,0,0,0},{0,0,0,0},{0,0,0,0}};
    #pragma unroll
    for (int nt = 0; nt < 3; ++nt){
        int f = nt * 16 + r0;
        int fr = (f < 40) ? f : 39;
        const float* wp = Wc + (size_t)fr * 64 + rg * 8;
        #pragma unroll
        for (int ks = 0; ks < 2; ++ks){
            short8v b_hi, b_lo;
            #pragma unroll
            for (int j = 0; j < 8; ++j){
                float v = wp[ks * 32 + j];
                short h = bf16t(v);
                b_hi[j] = h;
                b_lo[j] = bf16t(v - bf16tof(h));
            }
            acc[nt] = __builtin_amdgcn_mfma_f32_16x16x32_bf16(a_hi[ks], b_hi, acc[nt], 0, 0, 0);
            acc[nt] = __builtin_amdgcn_mfma_f32_16x16x32_bf16(a_hi[ks], b_lo, acc[nt], 0, 0, 0);
            acc[nt] = __builtin_amdgcn_mfma_f32_16x16x32_bf16(a_lo[ks], b_hi, acc[nt], 0, 0, 0);
        }
    }

    float bcv[3];
    #pragma unroll
    for (int nt = 0; nt < 3; ++nt){
        int f = nt * 16 + r0;
        bcv[nt] = (f < 40) ? bc[f] : 0.f;
    }

    #pragma unroll
    for (int q = 0; q < 4; ++q){
        int node = nb + rg * 4 + q;
        float l0 = acc[0][q] + bcv[0];
        float l1 = acc[1][q] + bcv[1];
        float l2 = (32 + r0 < 40) ? acc[2][q] + bcv[2] : -INFINITY;
        float m = fmaxf(l0, fmaxf(l1, l2));
        #pragma unroll
        for (int off = 8; off; off >>= 1) m = fmaxf(m, __shfl_xor(m, off));
        float s = __expf(l0 - m) + __expf(l1 - m) + ((32 + r0 < 40) ? __expf(l2 - m) : 0.f);
        #pragma unroll
        for (int off = 8; off; off >>= 1) s += __shfl_xor(s, off);
        float lse = m + __logf(s);
        if (node < n){
            out[(size_t)node * 40 + r0]      = l0 - lse;
            out[(size_t)node * 40 + 16 + r0] = l1 - lse;
            if (32 + r0 < 40) out[(size_t)node * 40 + 32 + r0] = l2 - lse;
        }
    }
}

extern "C" void kernel_launch(void* const* d_in, const int* in_sizes, int n_in,
                              void* d_out, int out_size, void* d_ws, size_t ws_size,
                              hipStream_t stream){
    const float* x     = (const float*)d_in[0];
    const int*   ei    = (const int*)  d_in[1];
    const float* W1    = (const float*)d_in[2];
    const float* b1    = (const float*)d_in[3];
    const float* att1  = (const float*)d_in[4];
    const float* bias1 = (const float*)d_in[5];
    const float* W2    = (const float*)d_in[6];
    const float* b2    = (const float*)d_in[7];
    const float* att2  = (const float*)d_in[8];
    const float* bias2 = (const float*)d_in[9];
    const float* Wp1   = (const float*)d_in[10];
    const float* bp1   = (const float*)d_in[11];
    const float* Wp2   = (const float*)d_in[12];
    const float* bp2   = (const float*)d_in[13];
    float* out = (float*)d_out;

    // workspace carve (float offsets; ~19.9 MB; 16B-aligned blocks)
    float*    base     = (float*)d_ws;
    __half*   hh       = (__half*)base;                 // NN*64 halves (1.6M f)
    __half*   gh       = (__half*)(base + 1600000);     // NN*64 halves (1.6M f)
    unsigned* part     = (unsigned*)(base + 3200000);   // 800,000
    int*      csr      = (int*)(base + 4000000);        // 800,000
    int*      counts   = (int*)(base + 4800000);        // 12,544
    int*      rowstart = (int*)(base + 4812560);        // 50,001 (+pad)
    float*    ad       = base + 4862576;                // 50,000
    float*    as_      = base + 4912576;                // 50,000
    float*    Wc       = base + 4962576;                // 2,560
    float*    bc       = base + 4965136;                // 40 (+pad)

    const int* srcv = ei;
    const int* dstv = ei + NE;

    // fused front: lin1 | cntA | wcomb
    k_fuse0 <<<GB + NPB + 1, 256, 0, stream>>>(x, W1, b1, att1, hh, ad, as_,
                                               dstv, counts,
                                               Wp1, bp1, Wp2, bp2, Wc, bc);
    k_partC <<<NPB, 256, 0, stream>>>(srcv, dstv, counts, part);
    k_buildD<<<NBUK, 256, 0, stream>>>(part, counts, rowstart, csr);

    int nb = (NN + 3) / 4;     // 1 node per wave (k_agg)
    k_agg      <<<nb, 256, 0, stream>>>((const __half2*)hh, ad, as_, rowstart, csr,
                                        (const float2*)bias1, (__half2*)gh, NN);
    k_lin_mfma_h<<<GB, 256, 0, stream>>>(gh, W2, b2, att2, hh, ad, as_, NN);
    k_agg      <<<nb, 256, 0, stream>>>((const __half2*)hh, ad, as_, rowstart, csr,
                                        (const float2*)bias2, (__half2*)gh, NN);
    k_mlp_mfma <<<GB, 256, 0, stream>>>(gh, Wc, bc, out, NN);
}